// Round 22
// baseline (87.470 us; speedup 1.0000x reference)
//
#include <hip/hip_runtime.h>

#define ALPHA 0.3f
#define NT    50
#define B_    16
#define S_    160
#define RR    40
#define Q_    (RR / 4)            // 10 float4 per rel pair
#define NROW  (B_ * S_)           // 2560
#define NPAIR (B_ * S_ * S_)      // 409600
#define NSEG  (NT * NT)           // 2500
#define NREL4 (NPAIR * Q_)        // 4096000 float4 of rel
#define NCOL  (NT * RR + NT)      // 2050 compact floats per C row
#define CW    2052                // padded C row stride (floats), 8208B (16B-aligned)

typedef float v4f __attribute__((ext_vector_type(4)));

__global__ void zero_tab(float* __restrict__ tab, int n) {
    int i = blockIdx.x * blockDim.x + threadIdx.x;
    if (i < n) tab[i] = 0.0f;
}

// Inline counting-sort of one batch's tags (256 threads). Deterministic.
__device__ __forceinline__ void sort_batch(const int* __restrict__ adds, int b,
                                           int* s_start /*NT+1*/,
                                           int* s_list /*S_*/,
                                           int* s_tags /*S_*/) {
    int tid = threadIdx.x;
    if (tid < S_) s_tags[tid] = adds[b * S_ + tid];
    __syncthreads();
    if (tid < NT) {
        int c = 0;
        for (int i = 0; i < S_; i++) c += (s_tags[i] == tid);
        s_start[tid] = c;                 // counts first
    }
    __syncthreads();
    if (tid == 0) {
        int s = 0;
        for (int t = 0; t < NT; t++) { int c = s_start[t]; s_start[t] = s; s += c; }
        s_start[NT] = s;
    }
    __syncthreads();
    if (tid < NT) {
        int slot = s_start[tid];
        for (int i = 0; i < S_; i++)
            if (s_tags[i] == tid) s_list[slot++] = i;
    }
    __syncthreads();
}

// ---- stage 1: inline sort + gather-on-stage (sorted LDS) + sequential-range
// reduce. p1==0 block of each batch PUBLISHES its lists for stage2. ----
template <int TO_C>
__global__ __launch_bounds__(256) void stage1(const float* __restrict__ a_arc,
                                              const float4* __restrict__ a_rel4,
                                              const int* __restrict__ adds,
                                              int* __restrict__ colstart,
                                              int* __restrict__ collist,
                                              float* __restrict__ C,
                                              float* __restrict__ tab_arc,
                                              float* __restrict__ tab_rel) {
    __shared__ v4f   a_srt[S_ * Q_];      // 25600 B, sorted by tag rank
    __shared__ float aarc_srt[S_];        // 640 B
    __shared__ int   s_start[NT + 1];
    __shared__ int   s_list[S_];
    __shared__ int   s_tags[S_];
    int row = blockIdx.x;                 // b*S_ + p1
    int b   = row / S_;
    int p1  = row - b * S_;
    int tid = threadIdx.x;

    sort_batch(adds, b, s_start, s_list, s_tags);

    // publish lists for stage2 (one block per batch; writes hide under staging)
    if (p1 == 0) {
        if (tid <= NT) colstart[b * 64 + tid] = s_start[tid];
        if (tid < S_)  collist[b * S_ + tid]  = s_list[tid];
    }

    const v4f*   arow  = (const v4f*)(a_rel4 + (size_t)row * (S_ * Q_));
    const float* aarow = a_arc + (size_t)row * S_;

#pragma unroll
    for (int k = 0; k < 7; ++k) {         // 7*256 = 1792 >= 1600
        int idx = k * 256 + tid;
        if (idx < S_ * Q_) {
            int j = idx / Q_;
            int q = idx - j * Q_;
            a_srt[idx] = arow[s_list[j] * Q_ + q];
        }
    }
    if (tid < S_) aarc_srt[tid] = aarow[s_list[tid]];
    __syncthreads();

    int t1 = TO_C ? 0 : s_tags[p1];

    for (int cell = tid; cell < NT * Q_; cell += 256) {
        int t2 = cell / Q_;
        int q  = cell - t2 * Q_;
        int e  = s_start[t2];
        int e1 = s_start[t2 + 1];
        v4f acc = {0.f, 0.f, 0.f, 0.f};
        for (; e + 4 <= e1; e += 4) {
            v4f v0 = a_srt[(e + 0) * Q_ + q];
            v4f v1 = a_srt[(e + 1) * Q_ + q];
            v4f v2 = a_srt[(e + 2) * Q_ + q];
            v4f v3 = a_srt[(e + 3) * Q_ + q];
            acc += (v0 + v1) + (v2 + v3);
        }
        for (; e < e1; ++e) acc += a_srt[e * Q_ + q];
        if (TO_C) {
            ((v4f*)(C + (size_t)row * CW))[cell] = acc;
        } else {
            float* dst = tab_rel + (size_t)t1 * (NT * RR) + cell * 4;
            atomicAdd(dst + 0, acc.x); atomicAdd(dst + 1, acc.y);
            atomicAdd(dst + 2, acc.z); atomicAdd(dst + 3, acc.w);
        }
    }
    if (tid < NT) {
        int e  = s_start[tid];
        int e1 = s_start[tid + 1];
        float acc = 0.f;
        for (; e + 4 <= e1; e += 4) {
            acc += ((aarc_srt[e] + aarc_srt[e + 1])
                  + (aarc_srt[e + 2] + aarc_srt[e + 3]));
        }
        for (; e < e1; ++e) acc += aarc_srt[e];
        if (TO_C) C[(size_t)row * CW + NT * RR + tid] = acc;
        else      atomicAdd(tab_arc + t1 * NT + tid, acc);
    }
}

// ---- stage 2: reduce C rows grouped by t1 via published lists, NO atomics ----
__global__ __launch_bounds__(256) void stage2(const float* __restrict__ C,
                                              const int* __restrict__ colstart,
                                              const int* __restrict__ collist,
                                              float* __restrict__ tab_arc,
                                              float* __restrict__ tab_rel) {
    int t1 = blockIdx.y;
    int c  = blockIdx.x * 256 + threadIdx.x;
    if (c >= NCOL) return;
    float acc = 0.f;
    for (int b = 0; b < B_; b++) {
        int s0 = colstart[b * 64 + t1], s1 = colstart[b * 64 + t1 + 1];
        for (int j = s0; j < s1; j++) {
            int row = b * S_ + collist[b * S_ + j];
            acc += C[(size_t)row * CW + c];
        }
    }
    if (c < NT * RR) tab_rel[t1 * (NT * RR) + c] = acc;
    else             tab_arc[t1 * NT + (c - NT * RR)] = acc;
}

// ---- apply v9: STREAM-FIRST software pipeline; NT stores ----
__global__ __launch_bounds__(256) void apply_v9(const float* __restrict__ s_arc,
                                                const v4f* __restrict__ s_rel4,
                                                const int* __restrict__ pos,
                                                const float* __restrict__ tab_arc,
                                                const v4f* __restrict__ tab_rel4,
                                                float* __restrict__ out_arc,
                                                v4f* __restrict__ out_rel4) {
    int row = blockIdx.x;                 // b*S_ + p1
    int b   = row / S_;
    int p1  = row - b * S_;
    int tid = threadIdx.x;
    const int* posb = pos + b * S_;

    const v4f* srow = s_rel4   + (size_t)row * (S_ * Q_);
    v4f*       orow = out_rel4 + (size_t)row * (S_ * Q_);

    // 1) issue the stream loads FIRST (7 independent, no address deps)
    v4f sv[7];
#pragma unroll
    for (int k = 0; k < 7; ++k) {
        int e = k * 256 + tid;
        sv[k] = (e < S_ * Q_) ? srow[e] : (v4f){0.f, 0.f, 0.f, 0.f};
    }
    float sa = (tid < S_) ? s_arc[(size_t)row * S_ + tid] : 0.f;

    // 2) gather chain (hidden under the in-flight stream loads)
    int base = posb[p1] * NT;
    int p2a[7], qa[7];
    {
        int p2 = tid / Q_, q = tid - (tid / Q_) * Q_;
#pragma unroll
        for (int k = 0; k < 7; ++k) {
            p2a[k] = (p2 < S_) ? p2 : 0;
            qa[k]  = q;
            q  += 6;
            p2 += 25;
            if (q >= Q_) { q -= Q_; p2 += 1; }
        }
    }
    int tp[7];
#pragma unroll
    for (int k = 0; k < 7; ++k) tp[k] = posb[p2a[k]];
    v4f tv[7];
#pragma unroll
    for (int k = 0; k < 7; ++k) tv[k] = tab_rel4[(base + tp[k]) * Q_ + qa[k]];
    float ta = (tid < S_) ? tab_arc[base + posb[tid]] : 0.f;

    // 3) combine + NT store
#pragma unroll
    for (int k = 0; k < 7; ++k) {
        int e = k * 256 + tid;
        if (e < S_ * Q_)
            __builtin_nontemporal_store(sv[k] + ALPHA * tv[k], orow + e);
    }
    if (tid < S_)
        __builtin_nontemporal_store(sa + ALPHA * ta,
                                    out_arc + (size_t)row * S_ + tid);
}

extern "C" void kernel_launch(void* const* d_in, const int* in_sizes, int n_in,
                              void* d_out, int out_size, void* d_ws, size_t ws_size,
                              hipStream_t stream) {
    const float*  a_arc = (const float*)d_in[0];
    const float4* a_rel = (const float4*)d_in[1];
    const float*  s_arc = (const float*)d_in[2];
    const v4f*    s_rel = (const v4f*)d_in[3];
    const int*    adds  = (const int*)d_in[4];
    const int*    pos   = (const int*)d_in[5];

    // workspace layout
    float* tab_arc  = (float*)d_ws;                    // NSEG
    float* tab_rel  = tab_arc + NSEG;                  // NSEG*RR
    int*   colstart = (int*)(tab_rel + NSEG * RR);     // B_*64
    int*   collist  = colstart + B_ * 64;              // B_*S_
    float* C        = (float*)(collist + B_ * S_);     // NROW*CW
    C = (float*)(((uintptr_t)C + 15) & ~(uintptr_t)15);

    size_t need_lists = (size_t)(NSEG * (RR + 1)) * 4
                      + (size_t)(B_ * 64 + B_ * S_) * 4 + 16;
    size_t need_full  = need_lists + (size_t)NROW * CW * 4;

    float* out_arc = (float*)d_out;                    // NPAIR
    v4f*   out_rel = (v4f*)(out_arc + NPAIR);          // NREL4

    const int BLK = 256;

    if (ws_size >= need_full) {
        stage1<1><<<NROW, 256, 0, stream>>>(a_arc, a_rel, adds, colstart, collist,
                                            C, nullptr, nullptr);
        dim3 g2((NCOL + 255) / 256, NT);
        stage2<<<g2, 256, 0, stream>>>(C, colstart, collist, tab_arc, tab_rel);
    } else {
        int n_tab = NSEG * (RR + 1);
        zero_tab<<<(n_tab + BLK - 1) / BLK, BLK, 0, stream>>>(tab_arc, n_tab);
        stage1<0><<<NROW, 256, 0, stream>>>(a_arc, a_rel, adds, colstart, collist,
                                            nullptr, tab_arc, tab_rel);
    }

    apply_v9<<<NROW, 256, 0, stream>>>(s_arc, s_rel, pos, tab_arc,
                                       (const v4f*)tab_rel, out_arc, out_rel);
}

// Round 23
// 78.999 us; speedup vs baseline: 1.1072x; 1.1072x over previous
//
#include <hip/hip_runtime.h>

#define ALPHA 0.3f
#define NT    50
#define B_    16
#define S_    160
#define RR    40
#define Q_    (RR / 4)            // 10 float4 per rel pair
#define NROW  (B_ * S_)           // 2560
#define NPAIR (B_ * S_ * S_)      // 409600
#define NSEG  (NT * NT)           // 2500
#define NREL4 (NPAIR * Q_)        // 4096000 float4 of rel
#define NCOL  (NT * RR + NT)      // 2050 compact floats per C row
#define CW    2052                // padded C row stride (floats), 8208B (16B-aligned)

typedef float v4f __attribute__((ext_vector_type(4)));

__global__ void zero_tab(float* __restrict__ tab, int n) {
    int i = blockIdx.x * blockDim.x + threadIdx.x;
    if (i < n) tab[i] = 0.0f;
}

// ---- per-batch position lists: deterministic counting sort of adds[b][:] ----
__global__ void build_lists(const int* __restrict__ adds,
                            int* __restrict__ colstart,   // [B_][64]
                            int* __restrict__ collist) {  // [B_][S_]
    __shared__ int tags[S_];
    __shared__ int cnt[NT];
    __shared__ int start[NT + 1];
    int b   = blockIdx.x;
    int tid = threadIdx.x;
    if (tid < S_) tags[tid] = adds[b * S_ + tid];
    __syncthreads();
    if (tid < NT) {
        int c = 0;
        for (int i = 0; i < S_; i++) c += (tags[i] == tid);
        cnt[tid] = c;
    }
    __syncthreads();
    if (tid == 0) {
        int s = 0;
        for (int t = 0; t < NT; t++) { start[t] = s; s += cnt[t]; }
        start[NT] = s;
    }
    __syncthreads();
    if (tid <= NT) colstart[b * 64 + tid] = start[tid];
    if (tid < NT) {
        int slot = start[tid];
        for (int i = 0; i < S_; i++)
            if (tags[i] == tid) collist[b * S_ + slot++] = i;
    }
}

// ---- stage 1: gather-on-stage (row loaded into LDS PRE-SORTED by tag rank),
// sequential-range reduce. PLAIN loads; external lists (R22: inline sort −25µs).
template <int TO_C>
__global__ __launch_bounds__(256) void stage1(const float* __restrict__ a_arc,
                                              const float4* __restrict__ a_rel4,
                                              const int* __restrict__ adds,
                                              const int* __restrict__ colstart,
                                              const int* __restrict__ collist,
                                              float* __restrict__ C,
                                              float* __restrict__ tab_arc,
                                              float* __restrict__ tab_rel) {
    __shared__ v4f   a_srt[S_ * Q_];      // 25600 B, sorted by tag rank
    __shared__ float aarc_srt[S_];        // 640 B
    __shared__ int   s_start[NT + 1];
    __shared__ int   s_list[S_];
    int row = blockIdx.x;                 // b*S_ + p1
    int b   = row / S_;
    int tid = threadIdx.x;

    if (tid <= NT) s_start[tid] = colstart[b * 64 + tid];
    if (tid < S_)  s_list[tid]  = collist[b * S_ + tid];
    __syncthreads();

    const v4f*   arow  = (const v4f*)(a_rel4 + (size_t)row * (S_ * Q_));
    const float* aarow = a_arc + (size_t)row * S_;

#pragma unroll
    for (int k = 0; k < 7; ++k) {         // 7*256 = 1792 >= 1600
        int idx = k * 256 + tid;
        if (idx < S_ * Q_) {
            int j = idx / Q_;
            int q = idx - j * Q_;
            a_srt[idx] = arow[s_list[j] * Q_ + q];
        }
    }
    if (tid < S_) aarc_srt[tid] = aarow[s_list[tid]];
    __syncthreads();

    int t1 = TO_C ? 0 : adds[row];

    for (int cell = tid; cell < NT * Q_; cell += 256) {
        int t2 = cell / Q_;
        int q  = cell - t2 * Q_;
        int e  = s_start[t2];
        int e1 = s_start[t2 + 1];
        v4f acc = {0.f, 0.f, 0.f, 0.f};
        for (; e + 4 <= e1; e += 4) {
            v4f v0 = a_srt[(e + 0) * Q_ + q];
            v4f v1 = a_srt[(e + 1) * Q_ + q];
            v4f v2 = a_srt[(e + 2) * Q_ + q];
            v4f v3 = a_srt[(e + 3) * Q_ + q];
            acc += (v0 + v1) + (v2 + v3);
        }
        for (; e < e1; ++e) acc += a_srt[e * Q_ + q];
        if (TO_C) {
            ((v4f*)(C + (size_t)row * CW))[cell] = acc;
        } else {
            float* dst = tab_rel + (size_t)t1 * (NT * RR) + cell * 4;
            atomicAdd(dst + 0, acc.x); atomicAdd(dst + 1, acc.y);
            atomicAdd(dst + 2, acc.z); atomicAdd(dst + 3, acc.w);
        }
    }
    if (tid < NT) {
        int e  = s_start[tid];
        int e1 = s_start[tid + 1];
        float acc = 0.f;
        for (; e + 4 <= e1; e += 4) {
            acc += ((aarc_srt[e] + aarc_srt[e + 1])
                  + (aarc_srt[e + 2] + aarc_srt[e + 3]));
        }
        for (; e < e1; ++e) acc += aarc_srt[e];
        if (TO_C) C[(size_t)row * CW + NT * RR + tid] = acc;
        else      atomicAdd(tab_arc + t1 * NT + tid, acc);
    }
}

// ---- stage 2: reduce C rows grouped by t1 via per-batch lists, NO atomics ----
__global__ __launch_bounds__(256) void stage2(const float* __restrict__ C,
                                              const int* __restrict__ colstart,
                                              const int* __restrict__ collist,
                                              float* __restrict__ tab_arc,
                                              float* __restrict__ tab_rel) {
    int t1 = blockIdx.y;
    int c  = blockIdx.x * 256 + threadIdx.x;
    if (c >= NCOL) return;
    float acc = 0.f;
    for (int b = 0; b < B_; b++) {
        int s0 = colstart[b * 64 + t1], s1 = colstart[b * 64 + t1 + 1];
        for (int j = s0; j < s1; j++) {
            int row = b * S_ + collist[b * S_ + j];
            acc += C[(size_t)row * CW + c];
        }
    }
    if (c < NT * RR) tab_rel[t1 * (NT * RR) + c] = acc;
    else             tab_arc[t1 * NT + (c - NT * RR)] = acc;
}

// ---- apply v9: STREAM-FIRST software pipeline; NT stores ----
__global__ __launch_bounds__(256) void apply_v9(const float* __restrict__ s_arc,
                                                const v4f* __restrict__ s_rel4,
                                                const int* __restrict__ pos,
                                                const float* __restrict__ tab_arc,
                                                const v4f* __restrict__ tab_rel4,
                                                float* __restrict__ out_arc,
                                                v4f* __restrict__ out_rel4) {
    int row = blockIdx.x;                 // b*S_ + p1
    int b   = row / S_;
    int p1  = row - b * S_;
    int tid = threadIdx.x;
    const int* posb = pos + b * S_;

    const v4f* srow = s_rel4   + (size_t)row * (S_ * Q_);
    v4f*       orow = out_rel4 + (size_t)row * (S_ * Q_);

    // 1) issue the stream loads FIRST (7 independent, no address deps)
    v4f sv[7];
#pragma unroll
    for (int k = 0; k < 7; ++k) {
        int e = k * 256 + tid;
        sv[k] = (e < S_ * Q_) ? srow[e] : (v4f){0.f, 0.f, 0.f, 0.f};
    }
    float sa = (tid < S_) ? s_arc[(size_t)row * S_ + tid] : 0.f;

    // 2) gather chain (hidden under the in-flight stream loads)
    int base = posb[p1] * NT;
    int p2a[7], qa[7];
    {
        int p2 = tid / Q_, q = tid - (tid / Q_) * Q_;
#pragma unroll
        for (int k = 0; k < 7; ++k) {
            p2a[k] = (p2 < S_) ? p2 : 0;
            qa[k]  = q;
            q  += 6;
            p2 += 25;
            if (q >= Q_) { q -= Q_; p2 += 1; }
        }
    }
    int tp[7];
#pragma unroll
    for (int k = 0; k < 7; ++k) tp[k] = posb[p2a[k]];
    v4f tv[7];
#pragma unroll
    for (int k = 0; k < 7; ++k) tv[k] = tab_rel4[(base + tp[k]) * Q_ + qa[k]];
    float ta = (tid < S_) ? tab_arc[base + posb[tid]] : 0.f;

    // 3) combine + NT store
#pragma unroll
    for (int k = 0; k < 7; ++k) {
        int e = k * 256 + tid;
        if (e < S_ * Q_)
            __builtin_nontemporal_store(sv[k] + ALPHA * tv[k], orow + e);
    }
    if (tid < S_)
        __builtin_nontemporal_store(sa + ALPHA * ta,
                                    out_arc + (size_t)row * S_ + tid);
}

extern "C" void kernel_launch(void* const* d_in, const int* in_sizes, int n_in,
                              void* d_out, int out_size, void* d_ws, size_t ws_size,
                              hipStream_t stream) {
    const float*  a_arc = (const float*)d_in[0];
    const float4* a_rel = (const float4*)d_in[1];
    const float*  s_arc = (const float*)d_in[2];
    const v4f*    s_rel = (const v4f*)d_in[3];
    const int*    adds  = (const int*)d_in[4];
    const int*    pos   = (const int*)d_in[5];

    // workspace layout
    float* tab_arc  = (float*)d_ws;                    // NSEG
    float* tab_rel  = tab_arc + NSEG;                  // NSEG*RR
    int*   colstart = (int*)(tab_rel + NSEG * RR);     // B_*64
    int*   collist  = colstart + B_ * 64;              // B_*S_
    float* C        = (float*)(collist + B_ * S_);     // NROW*CW
    C = (float*)(((uintptr_t)C + 15) & ~(uintptr_t)15);

    size_t need_lists = (size_t)(NSEG * (RR + 1)) * 4
                      + (size_t)(B_ * 64 + B_ * S_) * 4 + 16;
    size_t need_full  = need_lists + (size_t)NROW * CW * 4;

    float* out_arc = (float*)d_out;                    // NPAIR
    v4f*   out_rel = (v4f*)(out_arc + NPAIR);          // NREL4

    const int BLK = 256;

    build_lists<<<B_, 192, 0, stream>>>(adds, colstart, collist);

    if (ws_size >= need_full) {
        stage1<1><<<NROW, 256, 0, stream>>>(a_arc, a_rel, adds, colstart, collist,
                                            C, nullptr, nullptr);
        dim3 g2((NCOL + 255) / 256, NT);
        stage2<<<g2, 256, 0, stream>>>(C, colstart, collist, tab_arc, tab_rel);
    } else {
        int n_tab = NSEG * (RR + 1);
        zero_tab<<<(n_tab + BLK - 1) / BLK, BLK, 0, stream>>>(tab_arc, n_tab);
        stage1<0><<<NROW, 256, 0, stream>>>(a_arc, a_rel, adds, colstart, collist,
                                            nullptr, tab_arc, tab_rel);
    }

    apply_v9<<<NROW, 256, 0, stream>>>(s_arc, s_rel, pos, tab_arc,
                                       (const v4f*)tab_rel, out_arc, out_rel);
}